// Round 6
// baseline (2475.618 us; speedup 1.0000x reference)
//
#include <hip/hip_runtime.h>

// Swin window attention, fused per-window kernel, round 6.
// Round-5 residual: scheduler hoisted all 48 unrolled B-frag loads (~192 VGPR)
// -> scratch spills (WRITE 542 MB vs 308 MB out). Fix is codegen-shaping only:
//  - run_chunk: fully-unrolled depth-2 pipeline (pb[2][4], static afr indices)
//    with per-k2 sched_group_barrier(VMEM_READ x4, MFMA x4) to cap the in-flight
//    load window at 8 frags and interleave loads with MFMAs (T19).
//  - x->bf16 conversion loop gets the same VMEM/VALU grouping.
//  - proj reuses the dead afr registers for O fragments.
// Structure (proven correct in r5): per-head-group c-loop {q,K,V chunk GEMMs ->
// LDS; barrier; 4-head attention with swapped QK^T, in-register softmax,
// register-shuffle P->A-frags, O over q stripe; barrier}; then proj GEMM.

#define NTOK 49
#define DIM 384
#define HEADS 12
#define QKV_ELEMS (1152*384)
#define PROJ_ELEMS (384*384)
#define CMB_ELEMS (64*12*49*49)
#define SCALE 0.17677669529663687f

typedef __attribute__((ext_vector_type(8))) __bf16 bf16x8;
typedef __attribute__((ext_vector_type(4))) float f32x4;

union BF8 { bf16x8 v; unsigned short u[8]; };

__device__ __forceinline__ unsigned short f2bf(float f) {
  union { float f; unsigned u; } x; x.f = f;
  unsigned r = x.u + 0x7fffu + ((x.u >> 16) & 1u);   // RNE
  return (unsigned short)(r >> 16);
}

__device__ __forceinline__ bf16x8 zbf8() {
  BF8 z;
  #pragma unroll
  for (int j = 0; j < 8; ++j) z.u[j] = 0;
  return z.v;
}

__global__ void prep_kernel(const float* __restrict__ qkv_w,
                            const float* __restrict__ proj_w,
                            const float* __restrict__ bias_table,
                            const int* __restrict__ rel_idx,
                            const float* __restrict__ mask,
                            unsigned short* __restrict__ wq,
                            unsigned short* __restrict__ wp,
                            float* __restrict__ cmb) {
  int i = blockIdx.x * 256 + threadIdx.x;
  if (i < QKV_ELEMS) {
    wq[i] = f2bf(qkv_w[i]);
  } else if (i < QKV_ELEMS + PROJ_ELEMS) {
    int j = i - QKV_ELEMS;
    wp[j] = f2bf(proj_w[j]);
  } else if (i < QKV_ELEMS + PROJ_ELEMS + CMB_ELEMS) {
    int j = i - QKV_ELEMS - PROJ_ELEMS;
    // layout: ((wi*12 + h)*49 + tok)*49 + row   (row = query row)
    int row = j % 49;
    int tok = (j / 49) % 49;
    int h   = (j / 2401) % 12;
    int wi  = j / (2401 * 12);
    cmb[j] = bias_table[rel_idx[row * 49 + tok] * HEADS + h]
           + mask[(wi * 49 + row) * 49 + tok];
  }
}

// LDS element offsets (u16 units)
#define OFF_R1 0                        // [49][384] swizzled: q stripes -> O
#define OFF_K  (49*384)                 // [49][128] swizzled K chunk
#define OFF_VT (OFF_K + 49*128)         // [128][64] swizzled vT chunk
#define LDS_ELEMS (OFF_VT + 128*64)
#define LDS_BYTES (LDS_ELEMS*2)         // 66560 B -> 2 blocks/CU

__device__ __forceinline__ int swzq(int row, int colE) {   // stride 384
  return row * 384 + (colE ^ ((row & 7) << 3));
}
__device__ __forceinline__ int swzk(int row, int colE) {   // stride 128
  return row * 128 + (colE ^ ((row & 7) << 3));
}
__device__ __forceinline__ int swzv(int ch, int tokE) {    // stride 64
  return ch * 64 + (tokE ^ ((ch & 7) << 3));
}

__global__ __launch_bounds__(512, 4) void fused_win_attn(
    const float* __restrict__ x,
    const float* __restrict__ qkv_b, const float* __restrict__ proj_b,
    const unsigned short* __restrict__ wq, const unsigned short* __restrict__ wp,
    const float* __restrict__ cmb, float* __restrict__ out) {
  extern __shared__ unsigned short lds[];
  unsigned short* r1 = lds + OFF_R1;   // q stripes -> O
  unsigned short* kB = lds + OFF_K;    // K chunk [49][128] swizzled
  unsigned short* vT = lds + OFF_VT;   // V chunk transposed [128][64] swizzled

  const int tid  = threadIdx.x;
  const int wave = tid >> 6, lane = tid & 63;
  const int g = lane >> 4, li = lane & 15;
  const int win = blockIdx.x, wi = win & 63;
  const int mgrp = wave >> 1, ng = wave & 1;   // 4 M-tiles x 2 N-halves
  const int arow = mgrp * 16 + li;             // this wave's A/q row (lane li)

  // zero vT (pad tokens must be exact 0 for the PV MFMA)
  {
    uint4 z4 = {0u, 0u, 0u, 0u};
    uint4* p = (uint4*)(lds + OFF_VT);
    p[tid] = z4;
    p[tid + 512] = z4;
  }

  // ---- A-fragments for this wave's m-tile (fp32 -> bf16), persistent ----
  // SGB per iter: 2 VMEM loads then the conversion VALU burst, so the 24
  // float4 loads are not all hoisted (would be 96 VGPRs in flight).
  bf16x8 afr[12];
  if (arow < NTOK) {
    const float* xr = x + ((long)win * NTOK + arow) * DIM + g * 8;
    #pragma unroll
    for (int ks = 0; ks < 12; ++ks) {
      float4 f0 = *(const float4*)(xr + ks * 32);
      float4 f1 = *(const float4*)(xr + ks * 32 + 4);
      BF8 t;
      t.u[0] = f2bf(f0.x); t.u[1] = f2bf(f0.y); t.u[2] = f2bf(f0.z); t.u[3] = f2bf(f0.w);
      t.u[4] = f2bf(f1.x); t.u[5] = f2bf(f1.y); t.u[6] = f2bf(f1.z); t.u[7] = f2bf(f1.w);
      afr[ks] = t.v;
      __builtin_amdgcn_sched_group_barrier(0x020, 2, 0);   // 2 VMEM reads
      __builtin_amdgcn_sched_group_barrier(0x002, 24, 0);  // conversion VALU
    }
  } else {
    bf16x8 z = zbf8();
    #pragma unroll
    for (int ks = 0; ks < 12; ++ks) afr[ks] = z;
  }

  // chunk GEMM: 64 output cols/wave (4 n-tiles), B-frags from L2, depth-2
  // pipelined with a 2-buffer rotation; SGB pins [ld k2+1][mfma k2] pairs.
  auto run_chunk = [&](const unsigned short* wbase, int colbase, f32x4 acc[4]) {
    const unsigned short* b0 = wbase + (size_t)(colbase + li) * DIM + g * 8;
    bf16x8 pb[2][4];
    #pragma unroll
    for (int n = 0; n < 4; ++n)
      pb[0][n] = *(const bf16x8*)(b0 + n * 16 * DIM);
    #pragma unroll
    for (int k2 = 0; k2 < 12; ++k2) {
      const int cu = k2 & 1, nx = cu ^ 1;
      if (k2 < 11) {
        #pragma unroll
        for (int n = 0; n < 4; ++n)
          pb[nx][n] = *(const bf16x8*)(b0 + n * 16 * DIM + (k2 + 1) * 32);
      }
      acc[0] = __builtin_amdgcn_mfma_f32_16x16x32_bf16(afr[k2], pb[cu][0], acc[0], 0, 0, 0);
      acc[1] = __builtin_amdgcn_mfma_f32_16x16x32_bf16(afr[k2], pb[cu][1], acc[1], 0, 0, 0);
      acc[2] = __builtin_amdgcn_mfma_f32_16x16x32_bf16(afr[k2], pb[cu][2], acc[2], 0, 0, 0);
      acc[3] = __builtin_amdgcn_mfma_f32_16x16x32_bf16(afr[k2], pb[cu][3], acc[3], 0, 0, 0);
      __builtin_amdgcn_sched_group_barrier(0x020, 4, 0);   // 4 VMEM reads
      __builtin_amdgcn_sched_group_barrier(0x008, 4, 0);   // 4 MFMAs
    }
  };

  // ================= head-group pipeline: c = 0..2 =================
  #pragma unroll 1
  for (int c = 0; c < 3; ++c) {
    __syncthreads();   // Kbuf/vT free (prev attention done); iter0: vT zeros

    // ---- q chunk c -> r1 stripe (scale folded) ----
    {
      f32x4 acc[4];
      #pragma unroll
      for (int i = 0; i < 4; ++i) acc[i] = (f32x4){0.f, 0.f, 0.f, 0.f};
      run_chunk(wq, c * 128 + ng * 64, acc);
      #pragma unroll
      for (int nt = 0; nt < 4; ++nt) {
        int colg = c * 128 + ng * 64 + nt * 16 + li;
        float qb = qkv_b[colg];
        #pragma unroll
        for (int r4 = 0; r4 < 4; ++r4) {
          int row = mgrp * 16 + g * 4 + r4;
          if (row < NTOK) r1[swzq(row, colg)] = f2bf((acc[nt][r4] + qb) * SCALE);
        }
      }
    }
    // ---- K chunk c -> Kbuf ----
    {
      f32x4 acc[4];
      #pragma unroll
      for (int i = 0; i < 4; ++i) acc[i] = (f32x4){0.f, 0.f, 0.f, 0.f};
      run_chunk(wq, 384 + c * 128 + ng * 64, acc);
      #pragma unroll
      for (int nt = 0; nt < 4; ++nt) {
        int kcol = ng * 64 + nt * 16 + li;
        float qb = qkv_b[384 + c * 128 + kcol];
        #pragma unroll
        for (int r4 = 0; r4 < 4; ++r4) {
          int row = mgrp * 16 + g * 4 + r4;
          if (row < NTOK) kB[swzk(row, kcol)] = f2bf(acc[nt][r4] + qb);
        }
      }
    }
    // ---- V chunk c -> vT (transposed) ----
    {
      f32x4 acc[4];
      #pragma unroll
      for (int i = 0; i < 4; ++i) acc[i] = (f32x4){0.f, 0.f, 0.f, 0.f};
      run_chunk(wq, 768 + c * 128 + ng * 64, acc);
      #pragma unroll
      for (int nt = 0; nt < 4; ++nt) {
        int ch = ng * 64 + nt * 16 + li;
        float qb = qkv_b[768 + c * 128 + ch];
        #pragma unroll
        for (int r4 = 0; r4 < 4; ++r4) {
          int row = mgrp * 16 + g * 4 + r4;
          if (row < NTOK) vT[swzv(ch, row)] = f2bf(acc[nt][r4] + qb);
        }
      }
    }
    __syncthreads();   // q stripe, Kbuf, vT ready

    // ---- attention for the 4 heads of group c; 2 tasks per wave ----
    #pragma unroll 1
    for (int b = 0; b < 2; ++b) {
      const int hh = ng * 2 + b;        // head within chunk (0..3)
      const int h  = c * 4 + hh;        // global head

      bf16x8 qa = (arow < NTOK)
          ? *(const bf16x8*)&r1[swzq(arow, h * 32 + g * 8)] : zbf8();

      // S^T = mfma(K, q): rows = key toks, cols = q rows
      f32x4 sv[4];
      #pragma unroll
      for (int nt = 0; nt < 4; ++nt) {
        int tok = nt * 16 + li;
        bf16x8 kf = (tok < NTOK)
            ? *(const bf16x8*)&kB[swzk(tok, hh * 32 + g * 8)] : zbf8();
        f32x4 z4 = (f32x4){0.f, 0.f, 0.f, 0.f};
        sv[nt] = __builtin_amdgcn_mfma_f32_16x16x32_bf16(kf, qa, z4, 0, 0, 0);
      }

      // + combined bias+mask (layout [tok][qrow]); pad toks -> -1e30
      const float* cb = cmb + (size_t)(wi * HEADS + h) * (NTOK * NTOK);
      #pragma unroll
      for (int nt = 0; nt < 4; ++nt) {
        #pragma unroll
        for (int r4 = 0; r4 < 4; ++r4) {
          int tok = nt * 16 + g * 4 + r4;
          float v;
          if (tok < NTOK) {
            v = sv[nt][r4];
            if (arow < NTOK) v += cb[tok * NTOK + arow];
          } else {
            v = -1e30f;
          }
          sv[nt][r4] = v;
        }
      }

      // softmax over toks for fixed qrow=arow: 16 local + xor 16,32
      float m = -1e30f;
      #pragma unroll
      for (int nt = 0; nt < 4; ++nt)
        #pragma unroll
        for (int r4 = 0; r4 < 4; ++r4) m = fmaxf(m, sv[nt][r4]);
      m = fmaxf(m, __shfl_xor(m, 16));
      m = fmaxf(m, __shfl_xor(m, 32));
      float s = 0.f;
      #pragma unroll
      for (int nt = 0; nt < 4; ++nt)
        #pragma unroll
        for (int r4 = 0; r4 < 4; ++r4) {
          float e = __expf(sv[nt][r4] - m);
          sv[nt][r4] = e;
          s += e;
        }
      s += __shfl_xor(s, 16);
      s += __shfl_xor(s, 32);
      float inv = 1.f / s;
      #pragma unroll
      for (int nt = 0; nt < 4; ++nt)
        #pragma unroll
        for (int r4 = 0; r4 < 4; ++r4) sv[nt][r4] *= inv;

      // P (S^T layout) -> PV A-frags via register shuffles
      bf16x8 pa[2];
      #pragma unroll
      for (int k2 = 0; k2 < 2; ++k2) {
        BF8 pf;
        #pragma unroll
        for (int j = 0; j < 8; ++j) {
          int srcLane = (((g * 2 + (j >> 2)) & 3) << 4) | li;
          float v0 = __shfl(sv[k2 * 2][j & 3], srcLane);
          float v1 = __shfl(sv[k2 * 2 + 1][j & 3], srcLane);
          pf.u[j] = f2bf((g >= 2) ? v1 : v0);
        }
        pa[k2] = pf.v;
      }

      // O = P V (vT b128 reads; pad toks zero)
      f32x4 oa[2];
      oa[0] = (f32x4){0.f, 0.f, 0.f, 0.f};
      oa[1] = (f32x4){0.f, 0.f, 0.f, 0.f};
      #pragma unroll
      for (int k2 = 0; k2 < 2; ++k2) {
        #pragma unroll
        for (int nt2 = 0; nt2 < 2; ++nt2) {
          bf16x8 vb = *(const bf16x8*)&vT[swzv(hh * 32 + nt2 * 16 + li, k2 * 32 + g * 8)];
          oa[nt2] = __builtin_amdgcn_mfma_f32_16x16x32_bf16(pa[k2], vb, oa[nt2], 0, 0, 0);
        }
      }

      // O overwrites this head's q stripe
      #pragma unroll
      for (int nt2 = 0; nt2 < 2; ++nt2) {
        int col = h * 32 + nt2 * 16 + li;
        #pragma unroll
        for (int r4 = 0; r4 < 4; ++r4) {
          int row = mgrp * 16 + g * 4 + r4;
          if (row < NTOK) r1[swzq(row, col)] = f2bf(oa[nt2][r4]);
        }
      }
    }
  }
  __syncthreads();

  // ---- proj GEMM from O (r1); reuse afr registers for O fragments ----
  if (arow < NTOK) {
    #pragma unroll
    for (int ks = 0; ks < 12; ++ks)
      afr[ks] = *(const bf16x8*)&r1[swzq(arow, ks * 32 + g * 8)];
  } else {
    bf16x8 z = zbf8();
    #pragma unroll
    for (int ks = 0; ks < 12; ++ks) afr[ks] = z;
  }
  #pragma unroll 1
  for (int pc = 0; pc < 3; ++pc) {
    f32x4 acc[4];
    #pragma unroll
    for (int i = 0; i < 4; ++i) acc[i] = (f32x4){0.f, 0.f, 0.f, 0.f};
    run_chunk(wp, pc * 128 + ng * 64, acc);
    #pragma unroll
    for (int nt = 0; nt < 4; ++nt) {
      int col = pc * 128 + ng * 64 + nt * 16 + li;
      float pb = proj_b[col];
      #pragma unroll
      for (int r4 = 0; r4 < 4; ++r4) {
        int row = mgrp * 16 + g * 4 + r4;
        if (row < NTOK)
          out[((long)win * NTOK + row) * DIM + col] = acc[nt][r4] + pb;
      }
    }
  }
}

extern "C" void kernel_launch(void* const* d_in, const int* in_sizes, int n_in,
                              void* d_out, int out_size, void* d_ws, size_t ws_size,
                              hipStream_t stream) {
  (void)in_sizes; (void)n_in; (void)out_size; (void)ws_size;
  const float* x          = (const float*)d_in[0];
  const float* mask       = (const float*)d_in[1];
  const float* qkv_w      = (const float*)d_in[2];
  const float* qkv_b      = (const float*)d_in[3];
  const float* proj_w     = (const float*)d_in[4];
  const float* proj_b     = (const float*)d_in[5];
  const float* bias_table = (const float*)d_in[6];
  const int*   rel_idx    = (const int*)d_in[7];
  float* out = (float*)d_out;

  unsigned short* wq = (unsigned short*)d_ws;
  unsigned short* wp = wq + QKV_ELEMS;
  float* cmb = (float*)((char*)d_ws + (size_t)(QKV_ELEMS + PROJ_ELEMS) * 2);

  const int prep_total = QKV_ELEMS + PROJ_ELEMS + CMB_ELEMS;
  prep_kernel<<<(prep_total + 255) / 256, 256, 0, stream>>>(
      qkv_w, proj_w, bias_table, rel_idx, mask, wq, wp, cmb);
  fused_win_attn<<<4096, 512, LDS_BYTES, stream>>>(
      x, qkv_b, proj_b, wq, wp, cmb, out);
}

// Round 7
// 2173.996 us; speedup vs baseline: 1.1387x; 1.1387x over previous
//
#include <hip/hip_runtime.h>

// Swin window attention, round 7: batched SPLIT pipeline.
// r2-r6 evidence: fused-per-window forces per-wave weight re-reads from L2
// (~19 GB) and register-pressure spills; MfmaUtil never exceeded 8%.
// New structure, per batch of WB windows (WB chosen from ws_size):
//   1. convx: x -> bf16 xb                    [WB*49 x 384]
//   2. gemm64<bf16>: qkv = xb @ wq^T + qb2    (wq has softmax scale folded
//      into q rows at prep; weight panel BN=64 staged ONCE in LDS, 49 KB,
//      3 blocks/CU, one barrier; A streamed from global bf16)
//   3. attn: per-window kernel (round-5 verified math: swapped QK^T,
//      in-register softmax, register-shuffle P->A-frags); q/K/V staged from
//      qkv buffer; O written to xb (dead after gemm1)
//   4. gemm64<fp32>: out = O @ wp^T + proj_b
// prep also builds cmb[wi][h][tok][qrow] = bias+mask and scaled qb2.

#define NTOK 49
#define DIM 384
#define HEADS 12
#define QKV_OC 1152
#define QKV_ELEMS (1152*384)
#define PROJ_ELEMS (384*384)
#define CMB_ELEMS (64*12*49*49)
#define SCALE 0.17677669529663687f

typedef __attribute__((ext_vector_type(8))) __bf16 bf16x8;
typedef __attribute__((ext_vector_type(4))) float f32x4;

union BF8 { bf16x8 v; unsigned short u[8]; uint4 q; };

__device__ __forceinline__ unsigned short f2bf(float f) {
  union { float f; unsigned u; } x; x.f = f;
  unsigned r = x.u + 0x7fffu + ((x.u >> 16) & 1u);   // RNE
  return (unsigned short)(r >> 16);
}

__device__ __forceinline__ bf16x8 zbf8() {
  BF8 z;
  #pragma unroll
  for (int j = 0; j < 8; ++j) z.u[j] = 0;
  return z.v;
}

// ---------------- prep: weights->bf16 (scale folded), cmb, scaled bias ----
__global__ void prep_kernel(const float* __restrict__ qkv_w,
                            const float* __restrict__ proj_w,
                            const float* __restrict__ bias_table,
                            const int* __restrict__ rel_idx,
                            const float* __restrict__ mask,
                            const float* __restrict__ qkv_b,
                            unsigned short* __restrict__ wq,
                            unsigned short* __restrict__ wp,
                            float* __restrict__ cmb,
                            float* __restrict__ qb2) {
  int i = blockIdx.x * 256 + threadIdx.x;
  if (i < QKV_ELEMS) {
    float v = qkv_w[i];
    if (i < 384 * 384) v *= SCALE;            // q rows get the softmax scale
    wq[i] = f2bf(v);
  } else if (i < QKV_ELEMS + PROJ_ELEMS) {
    int j = i - QKV_ELEMS;
    wp[j] = f2bf(proj_w[j]);
  } else if (i < QKV_ELEMS + PROJ_ELEMS + CMB_ELEMS) {
    int j = i - QKV_ELEMS - PROJ_ELEMS;
    // layout: ((wi*12 + h)*49 + tok)*49 + qrow
    int row = j % 49;
    int tok = (j / 49) % 49;
    int h   = (j / 2401) % 12;
    int wi  = j / (2401 * 12);
    cmb[j] = bias_table[rel_idx[row * 49 + tok] * HEADS + h]
           + mask[(wi * 49 + row) * 49 + tok];
  } else if (i < QKV_ELEMS + PROJ_ELEMS + CMB_ELEMS + QKV_OC) {
    int c = i - QKV_ELEMS - PROJ_ELEMS - CMB_ELEMS;
    qb2[c] = qkv_b[c] * (c < 384 ? SCALE : 1.0f);
  }
}

// ---------------- convx: fp32 -> bf16, 8 elems/thread ----------------
__global__ void convx_kernel(const float* __restrict__ x,
                             unsigned short* __restrict__ xb, long total) {
  long idx = ((long)blockIdx.x * 256 + threadIdx.x) * 8;
  if (idx >= total) return;
  float4 f0 = *(const float4*)(x + idx);
  float4 f1 = *(const float4*)(x + idx + 4);
  BF8 t;
  t.u[0] = f2bf(f0.x); t.u[1] = f2bf(f0.y); t.u[2] = f2bf(f0.z); t.u[3] = f2bf(f0.w);
  t.u[4] = f2bf(f1.x); t.u[5] = f2bf(f1.y); t.u[6] = f2bf(f1.z); t.u[7] = f2bf(f1.w);
  *(uint4*)(xb + idx) = t.q;
}

// ---------------- gemm64: C[M][Ntot] = A[M][384] @ W[Ntot][384]^T + bias ---
// BN=64 weight panel in LDS (swizzled), one barrier; 256 thr / 4 waves;
// each wave does 4 m-tiles of 16 rows (block = 256 rows).
template<int BF16OUT>
__global__ __launch_bounds__(256, 3) void gemm64(
    const unsigned short* __restrict__ A,
    const unsigned short* __restrict__ W,
    const float* __restrict__ bias,
    void* __restrict__ Cout, int Mrows, int Ntot, int NS) {
  __shared__ unsigned short Bsm[64 * 384];    // 49152 B
  const int nwg = gridDim.x;
  const int bid = blockIdx.x;
  // bijective XCD swizzle (m204)
  const int xcd = bid & 7, lin = bid >> 3;
  const int qq = nwg >> 3, rr = nwg & 7;
  const int wgid = (xcd < rr ? xcd * (qq + 1) : rr * (qq + 1) + (xcd - rr) * qq) + lin;
  const int ns = wgid % NS, mc = wgid / NS;
  const int tid = threadIdx.x;
  const int wave = tid >> 6, lane = tid & 63, g = lane >> 4, li = lane & 15;
  const int nb = ns * 64;

  // stage weight panel [64 out-cols][384 k], granule-swizzled
  #pragma unroll
  for (int i = 0; i < 12; ++i) {
    int gidx = i * 256 + tid;
    int row = gidx / 48, gc = gidx % 48;
    bf16x8 v = *(const bf16x8*)(W + (size_t)(nb + row) * 384 + gc * 8);
    *(bf16x8*)&Bsm[row * 384 + ((gc ^ (row & 7)) << 3)] = v;
  }
  __syncthreads();

  #pragma unroll 1
  for (int r = 0; r < 4; ++r) {
    const int tb = mc * 256 + (r * 4 + wave) * 16;
    const int arow = tb + li;
    bf16x8 afr[12];
    if (arow < Mrows) {
      const unsigned short* ap = A + (size_t)arow * 384 + g * 8;
      #pragma unroll
      for (int k2 = 0; k2 < 12; ++k2) afr[k2] = *(const bf16x8*)(ap + k2 * 32);
    } else {
      bf16x8 z = zbf8();
      #pragma unroll
      for (int k2 = 0; k2 < 12; ++k2) afr[k2] = z;
    }
    f32x4 acc[4];
    #pragma unroll
    for (int i = 0; i < 4; ++i) acc[i] = (f32x4){0.f, 0.f, 0.f, 0.f};
    #pragma unroll
    for (int k2 = 0; k2 < 12; ++k2) {
      #pragma unroll
      for (int nt = 0; nt < 4; ++nt) {
        int brow = nt * 16 + li;
        bf16x8 bf = *(const bf16x8*)&Bsm[brow * 384 + (((k2 * 4 + g) ^ (li & 7)) << 3)];
        acc[nt] = __builtin_amdgcn_mfma_f32_16x16x32_bf16(afr[k2], bf, acc[nt], 0, 0, 0);
      }
    }
    #pragma unroll
    for (int nt = 0; nt < 4; ++nt) {
      int col = nb + nt * 16 + li;
      float bv = bias[col];
      #pragma unroll
      for (int r4 = 0; r4 < 4; ++r4) {
        int row = tb + g * 4 + r4;
        if (row < Mrows) {
          float v = acc[nt][r4] + bv;
          if (BF16OUT) ((unsigned short*)Cout)[(size_t)row * Ntot + col] = f2bf(v);
          else         ((float*)Cout)[(size_t)row * Ntot + col] = v;
        }
      }
    }
  }
}

// ---------------- attn: per-window, q/K/V from qkv buffer ----------------
#define AT_Q 0                   // [49][384] swizzled (scaled q)
#define AT_K (49*384)            // [49][128] swizzled K chunk
#define AT_V (AT_K + 49*128)     // [49][138] plain V chunk (bank-spread)
#define AT_ELEMS (AT_V + 49*138) // 31850 elems = 63700 B -> 2 blocks/CU

__global__ __launch_bounds__(512, 4) void attn_kernel(
    const unsigned short* __restrict__ qkv,   // [WB*49][1152]
    const float* __restrict__ cmb,
    unsigned short* __restrict__ Obuf,        // [WB*49][384] (xb reuse)
    int wb0) {
  __shared__ unsigned short lds[AT_ELEMS];
  const int tid  = threadIdx.x;
  const int wave = tid >> 6, lane = tid & 63;
  const int g = lane >> 4, li = lane & 15;
  const int relw = blockIdx.x;
  const int wi = (wb0 + relw) & 63;
  const size_t rowbase = (size_t)relw * 49;
  const int mgrp = wave >> 1, ng = wave & 1;
  const int arow = mgrp * 16 + li;

  // stage q [49][384] (already scaled)
  #pragma unroll
  for (int it = 0; it < 5; ++it) {
    int gidx = it * 512 + tid;
    if (gidx < 2352) {
      int row = gidx / 48, gc = gidx % 48;
      bf16x8 v = *(const bf16x8*)(qkv + (rowbase + row) * 1152 + gc * 8);
      *(bf16x8*)&lds[AT_Q + row * 384 + ((gc ^ (row & 7)) << 3)] = v;
    }
  }

  #pragma unroll 1
  for (int c = 0; c < 3; ++c) {
    if (c) __syncthreads();        // prior compute done before K/V overwrite
    // stage K chunk [49][128] swizzled
    #pragma unroll
    for (int it = 0; it < 2; ++it) {
      int gidx = it * 512 + tid;
      if (gidx < 784) {
        int row = gidx >> 4, gc = gidx & 15;
        bf16x8 v = *(const bf16x8*)(qkv + (rowbase + row) * 1152 + 384 + c * 128 + gc * 8);
        *(bf16x8*)&lds[AT_K + row * 128 + ((gc ^ (row & 7)) << 3)] = v;
      }
    }
    // stage V chunk [49][138] row-major (stride 138: g-groups spread banks)
    #pragma unroll
    for (int it = 0; it < 2; ++it) {
      int gidx = it * 512 + tid;
      if (gidx < 784) {
        int row = gidx >> 4, gc = gidx & 15;
        BF8 v;
        v.q = *(const uint4*)(qkv + (rowbase + row) * 1152 + 768 + c * 128 + gc * 8);
        int e = AT_V + row * 138 + gc * 8;
        *(unsigned*)&lds[e]     = v.q.x;
        *(unsigned*)&lds[e + 2] = v.q.y;
        *(unsigned*)&lds[e + 4] = v.q.z;
        *(unsigned*)&lds[e + 6] = v.q.w;
      }
    }
    __syncthreads();

    #pragma unroll 1
    for (int b = 0; b < 2; ++b) {
      const int hh = ng * 2 + b;      // head within chunk
      const int h  = c * 4 + hh;      // global head

      bf16x8 qa = (arow < NTOK)
          ? *(const bf16x8*)&lds[AT_Q + arow * 384 + (((h * 4 + g) ^ (arow & 7)) << 3)]
          : zbf8();

      // S^T = mfma(K, q)
      f32x4 sv[4];
      #pragma unroll
      for (int nt = 0; nt < 4; ++nt) {
        int tok = nt * 16 + li;
        bf16x8 kf = (tok < NTOK)
            ? *(const bf16x8*)&lds[AT_K + tok * 128 + (((hh * 4 + g) ^ (tok & 7)) << 3)]
            : zbf8();
        f32x4 z4 = (f32x4){0.f, 0.f, 0.f, 0.f};
        sv[nt] = __builtin_amdgcn_mfma_f32_16x16x32_bf16(kf, qa, z4, 0, 0, 0);
      }

      // + combined bias+mask; pad toks -> -1e30
      const float* cb = cmb + (size_t)(wi * HEADS + h) * (NTOK * NTOK);
      #pragma unroll
      for (int nt = 0; nt < 4; ++nt) {
        #pragma unroll
        for (int r4 = 0; r4 < 4; ++r4) {
          int tok = nt * 16 + g * 4 + r4;
          float v;
          if (tok < NTOK) {
            v = sv[nt][r4];
            if (arow < NTOK) v += cb[tok * NTOK + arow];
          } else {
            v = -1e30f;
          }
          sv[nt][r4] = v;
        }
      }

      // softmax over toks for fixed qrow=arow
      float m = -1e30f;
      #pragma unroll
      for (int nt = 0; nt < 4; ++nt)
        #pragma unroll
        for (int r4 = 0; r4 < 4; ++r4) m = fmaxf(m, sv[nt][r4]);
      m = fmaxf(m, __shfl_xor(m, 16));
      m = fmaxf(m, __shfl_xor(m, 32));
      float s = 0.f;
      #pragma unroll
      for (int nt = 0; nt < 4; ++nt)
        #pragma unroll
        for (int r4 = 0; r4 < 4; ++r4) {
          float e = __expf(sv[nt][r4] - m);
          sv[nt][r4] = e;
          s += e;
        }
      s += __shfl_xor(s, 16);
      s += __shfl_xor(s, 32);
      float inv = 1.f / s;
      #pragma unroll
      for (int nt = 0; nt < 4; ++nt)
        #pragma unroll
        for (int r4 = 0; r4 < 4; ++r4) sv[nt][r4] *= inv;

      // P (S^T layout) -> PV A-frags via register shuffles
      bf16x8 pa[2];
      #pragma unroll
      for (int k2 = 0; k2 < 2; ++k2) {
        BF8 pf;
        #pragma unroll
        for (int j = 0; j < 8; ++j) {
          int srcLane = (((g * 2 + (j >> 2)) & 3) << 4) | li;
          float v0 = __shfl(sv[k2 * 2][j & 3], srcLane);
          float v1 = __shfl(sv[k2 * 2 + 1][j & 3], srcLane);
          pf.u[j] = f2bf((g >= 2) ? v1 : v0);
        }
        pa[k2] = pf.v;
      }

      // O = P V (V row-major gather, stride 138)
      f32x4 oa[2];
      oa[0] = (f32x4){0.f, 0.f, 0.f, 0.f};
      oa[1] = (f32x4){0.f, 0.f, 0.f, 0.f};
      #pragma unroll
      for (int k2 = 0; k2 < 2; ++k2) {
        #pragma unroll
        for (int nt2 = 0; nt2 < 2; ++nt2) {
          BF8 vb;
          int ch = hh * 32 + nt2 * 16 + li;
          #pragma unroll
          for (int j = 0; j < 8; ++j) {
            int tok = k2 * 32 + g * 8 + j;
            vb.u[j] = (tok < NTOK) ? lds[AT_V + tok * 138 + ch] : (unsigned short)0;
          }
          oa[nt2] = __builtin_amdgcn_mfma_f32_16x16x32_bf16(pa[k2], vb.v, oa[nt2], 0, 0, 0);
        }
      }

      // O -> Obuf (bf16, [49][384] per window)
      #pragma unroll
      for (int nt2 = 0; nt2 < 2; ++nt2) {
        int col = h * 32 + nt2 * 16 + li;
        #pragma unroll
        for (int r4 = 0; r4 < 4; ++r4) {
          int row = mgrp * 16 + g * 4 + r4;
          if (row < NTOK)
            Obuf[(rowbase + row) * 384 + col] = f2bf(oa[nt2][r4]);
        }
      }
    }
  }
}

extern "C" void kernel_launch(void* const* d_in, const int* in_sizes, int n_in,
                              void* d_out, int out_size, void* d_ws, size_t ws_size,
                              hipStream_t stream) {
  (void)in_sizes; (void)n_in; (void)out_size;
  const float* x          = (const float*)d_in[0];
  const float* mask       = (const float*)d_in[1];
  const float* qkv_w      = (const float*)d_in[2];
  const float* qkv_b      = (const float*)d_in[3];
  const float* proj_w     = (const float*)d_in[4];
  const float* proj_b     = (const float*)d_in[5];
  const float* bias_table = (const float*)d_in[6];
  const int*   rel_idx    = (const int*)d_in[7];
  float* out = (float*)d_out;

  char* ws = (char*)d_ws;
  size_t off = 0;
  unsigned short* wq  = (unsigned short*)(ws + off); off += (size_t)QKV_ELEMS * 2;   // 884736
  unsigned short* wp  = (unsigned short*)(ws + off); off += (size_t)PROJ_ELEMS * 2;  // 294912
  float*          qb2 = (float*)(ws + off);          off += (size_t)QKV_OC * 4;      // 4608
  float*          cmb = (float*)(ws + off);          off += (size_t)CMB_ELEMS * 4;   // 7375872
  const size_t fixed = off;

  // choose batch size WB (windows) to fit ws: xb + qkv buffers
  int WB = 64;
  for (int wb = 4096; wb >= 64; wb >>= 1) {
    size_t need = fixed + (size_t)wb * 49 * 384 * 2 + (size_t)wb * 49 * 1152 * 2;
    if (need <= ws_size) { WB = wb; break; }
  }
  unsigned short* xb  = (unsigned short*)(ws + fixed);
  unsigned short* qkv = xb + (size_t)WB * 49 * 384;

  const int prep_total = QKV_ELEMS + PROJ_ELEMS + CMB_ELEMS + QKV_OC;
  prep_kernel<<<(prep_total + 255) / 256, 256, 0, stream>>>(
      qkv_w, proj_w, bias_table, rel_idx, mask, qkv_b, wq, wp, cmb, qb2);

  const int NB = 4096 / WB;
  const int Mrows = WB * 49;
  const int mch = (Mrows + 255) / 256;
  const long xtot = (long)Mrows * 384;
  for (int b = 0; b < NB; ++b) {
    convx_kernel<<<(int)((xtot / 8 + 255) / 256), 256, 0, stream>>>(
        x + (size_t)b * Mrows * 384, xb, xtot);
    gemm64<1><<<mch * 18, 256, 0, stream>>>(xb, wq, qb2, (void*)qkv, Mrows, 1152, 18);
    attn_kernel<<<WB, 512, 0, stream>>>(qkv, cmb, xb, b * WB);
    gemm64<0><<<mch * 6, 256, 0, stream>>>(xb, wp, proj_b,
        (void*)(out + (size_t)b * Mrows * 384), Mrows, 384, 6);
  }
}

// Round 8
// 1233.713 us; speedup vs baseline: 2.0066x; 1.7622x over previous
//
#include <hip/hip_runtime.h>

// Swin window attention, round 8: split pipeline with A-resident GEMMs.
// r7 profile: qkv gemm64 fetched 3.1 GB (A re-read 18x, one per 64-col slice),
// 50% HBM peak, 1276 us. Fix: block owns 64 ROWS; A-frags loaded once into
// registers; loop over N-slices INSIDE the block, staging each 64x384 weight
// panel in LDS (49 KB, 3 blocks/CU). A read exactly once; W is L2/L3-resident.
// convx folded into the qkv GEMM (fp32 A path). Attn kernel unchanged from r7.

#define NTOK 49
#define DIM 384
#define HEADS 12
#define QKV_OC 1152
#define QKV_ELEMS (1152*384)
#define PROJ_ELEMS (384*384)
#define CMB_ELEMS (64*12*49*49)
#define SCALE 0.17677669529663687f

typedef __attribute__((ext_vector_type(8))) __bf16 bf16x8;
typedef __attribute__((ext_vector_type(4))) float f32x4;

union BF8 { bf16x8 v; unsigned short u[8]; uint4 q; };

__device__ __forceinline__ unsigned short f2bf(float f) {
  union { float f; unsigned u; } x; x.f = f;
  unsigned r = x.u + 0x7fffu + ((x.u >> 16) & 1u);   // RNE
  return (unsigned short)(r >> 16);
}

__device__ __forceinline__ bf16x8 zbf8() {
  BF8 z;
  #pragma unroll
  for (int j = 0; j < 8; ++j) z.u[j] = 0;
  return z.v;
}

// ---------------- prep: weights->bf16 (scale folded), cmb, scaled bias ----
__global__ void prep_kernel(const float* __restrict__ qkv_w,
                            const float* __restrict__ proj_w,
                            const float* __restrict__ bias_table,
                            const int* __restrict__ rel_idx,
                            const float* __restrict__ mask,
                            const float* __restrict__ qkv_b,
                            unsigned short* __restrict__ wq,
                            unsigned short* __restrict__ wp,
                            float* __restrict__ cmb,
                            float* __restrict__ qb2) {
  int i = blockIdx.x * 256 + threadIdx.x;
  if (i < QKV_ELEMS) {
    float v = qkv_w[i];
    if (i < 384 * 384) v *= SCALE;            // q rows get the softmax scale
    wq[i] = f2bf(v);
  } else if (i < QKV_ELEMS + PROJ_ELEMS) {
    int j = i - QKV_ELEMS;
    wp[j] = f2bf(proj_w[j]);
  } else if (i < QKV_ELEMS + PROJ_ELEMS + CMB_ELEMS) {
    int j = i - QKV_ELEMS - PROJ_ELEMS;
    // layout: ((wi*12 + h)*49 + tok)*49 + qrow
    int row = j % 49;
    int tok = (j / 49) % 49;
    int h   = (j / 2401) % 12;
    int wi  = j / (2401 * 12);
    cmb[j] = bias_table[rel_idx[row * 49 + tok] * HEADS + h]
           + mask[(wi * 49 + row) * 49 + tok];
  } else if (i < QKV_ELEMS + PROJ_ELEMS + CMB_ELEMS + QKV_OC) {
    int c = i - QKV_ELEMS - PROJ_ELEMS - CMB_ELEMS;
    qb2[c] = qkv_b[c] * (c < 384 ? SCALE : 1.0f);
  }
}

// ------- gemm_full: C[M][NS*64] = A[M][384] @ W[NS*64][384]^T + bias -------
// Block = 64 rows (4 waves x 16). A-frags persistent in registers (read once).
// Inner loop over NS column-slices; weight panel [64][384] staged in LDS
// (swizzled), 2 barriers/slice. 49 KB LDS -> 3 blocks/CU.
template<int NS, int FP32IN, int BF16OUT>
__global__ __launch_bounds__(256, 3) void gemm_full(
    const void* __restrict__ Ain, const unsigned short* __restrict__ W,
    const float* __restrict__ bias, void* __restrict__ Cout, int Mrows) {
  __shared__ alignas(16) unsigned short Bsm[64 * 384];   // 49152 B
  const int tid = threadIdx.x;
  const int wave = tid >> 6, lane = tid & 63, g = lane >> 4, li = lane & 15;
  const int tb = blockIdx.x * 64 + wave * 16;
  const int arow = tb + li;

  // A-fragments, loaded once (fp32->bf16 convert for the qkv gemm)
  bf16x8 afr[12];
  if (arow < Mrows) {
    if (FP32IN) {
      const float* ap = (const float*)Ain + (size_t)arow * 384 + g * 8;
      #pragma unroll
      for (int ks = 0; ks < 12; ++ks) {
        float4 f0 = *(const float4*)(ap + ks * 32);
        float4 f1 = *(const float4*)(ap + ks * 32 + 4);
        BF8 t;
        t.u[0] = f2bf(f0.x); t.u[1] = f2bf(f0.y); t.u[2] = f2bf(f0.z); t.u[3] = f2bf(f0.w);
        t.u[4] = f2bf(f1.x); t.u[5] = f2bf(f1.y); t.u[6] = f2bf(f1.z); t.u[7] = f2bf(f1.w);
        afr[ks] = t.v;
      }
    } else {
      const unsigned short* ap = (const unsigned short*)Ain + (size_t)arow * 384 + g * 8;
      #pragma unroll
      for (int ks = 0; ks < 12; ++ks) afr[ks] = *(const bf16x8*)(ap + ks * 32);
    }
  } else {
    bf16x8 z = zbf8();
    #pragma unroll
    for (int ks = 0; ks < 12; ++ks) afr[ks] = z;
  }

  #pragma unroll 1
  for (int ns = 0; ns < NS; ++ns) {
    if (ns) __syncthreads();              // all waves done reading prev panel
    // stage weight panel [64 cols][384 k], granule-swizzled: LDS slot s of a
    // row holds W granule s^(row&7)
    #pragma unroll
    for (int it = 0; it < 12; ++it) {
      int gi = it * 256 + tid;
      int row = gi / 48, gcs = gi % 48;
      int gc = gcs ^ (row & 7);
      bf16x8 v = *(const bf16x8*)(W + (size_t)(ns * 64 + row) * 384 + gc * 8);
      *(bf16x8*)&Bsm[row * 384 + gcs * 8] = v;
    }
    __syncthreads();

    f32x4 acc[4];
    #pragma unroll
    for (int i = 0; i < 4; ++i) acc[i] = (f32x4){0.f, 0.f, 0.f, 0.f};
    #pragma unroll
    for (int k2 = 0; k2 < 12; ++k2) {
      #pragma unroll
      for (int nt = 0; nt < 4; ++nt) {
        int brow = nt * 16 + li;
        bf16x8 bf = *(const bf16x8*)&Bsm[brow * 384 + (((k2 * 4 + g) ^ (li & 7)) << 3)];
        acc[nt] = __builtin_amdgcn_mfma_f32_16x16x32_bf16(afr[k2], bf, acc[nt], 0, 0, 0);
      }
    }
    #pragma unroll
    for (int nt = 0; nt < 4; ++nt) {
      int col = ns * 64 + nt * 16 + li;
      float bv = bias[col];
      #pragma unroll
      for (int r4 = 0; r4 < 4; ++r4) {
        int row = tb + g * 4 + r4;
        if (row < Mrows) {
          float v = acc[nt][r4] + bv;
          if (BF16OUT) ((unsigned short*)Cout)[(size_t)row * (NS * 64) + col] = f2bf(v);
          else         ((float*)Cout)[(size_t)row * (NS * 64) + col] = v;
        }
      }
    }
  }
}

// ---------------- attn: per-window, q/K/V from qkv buffer (r7 verbatim) ----
#define AT_Q 0                   // [49][384] swizzled (scaled q)
#define AT_K (49*384)            // [49][128] swizzled K chunk
#define AT_V (AT_K + 49*128)     // [49][138] plain V chunk (bank-spread)
#define AT_ELEMS (AT_V + 49*138)

__global__ __launch_bounds__(512, 4) void attn_kernel(
    const unsigned short* __restrict__ qkv,   // [WB*49][1152]
    const float* __restrict__ cmb,
    unsigned short* __restrict__ Obuf,        // [WB*49][384]
    int wb0) {
  __shared__ unsigned short lds[AT_ELEMS];
  const int tid  = threadIdx.x;
  const int wave = tid >> 6, lane = tid & 63;
  const int g = lane >> 4, li = lane & 15;
  const int relw = blockIdx.x;
  const int wi = (wb0 + relw) & 63;
  const size_t rowbase = (size_t)relw * 49;
  const int mgrp = wave >> 1, ng = wave & 1;
  const int arow = mgrp * 16 + li;

  // stage q [49][384] (already scaled)
  #pragma unroll
  for (int it = 0; it < 5; ++it) {
    int gidx = it * 512 + tid;
    if (gidx < 2352) {
      int row = gidx / 48, gc = gidx % 48;
      bf16x8 v = *(const bf16x8*)(qkv + (rowbase + row) * 1152 + gc * 8);
      *(bf16x8*)&lds[AT_Q + row * 384 + ((gc ^ (row & 7)) << 3)] = v;
    }
  }

  #pragma unroll 1
  for (int c = 0; c < 3; ++c) {
    if (c) __syncthreads();
    // stage K chunk [49][128] swizzled
    #pragma unroll
    for (int it = 0; it < 2; ++it) {
      int gidx = it * 512 + tid;
      if (gidx < 784) {
        int row = gidx >> 4, gc = gidx & 15;
        bf16x8 v = *(const bf16x8*)(qkv + (rowbase + row) * 1152 + 384 + c * 128 + gc * 8);
        *(bf16x8*)&lds[AT_K + row * 128 + ((gc ^ (row & 7)) << 3)] = v;
      }
    }
    // stage V chunk [49][138] row-major
    #pragma unroll
    for (int it = 0; it < 2; ++it) {
      int gidx = it * 512 + tid;
      if (gidx < 784) {
        int row = gidx >> 4, gc = gidx & 15;
        BF8 v;
        v.q = *(const uint4*)(qkv + (rowbase + row) * 1152 + 768 + c * 128 + gc * 8);
        int e = AT_V + row * 138 + gc * 8;
        *(unsigned*)&lds[e]     = v.q.x;
        *(unsigned*)&lds[e + 2] = v.q.y;
        *(unsigned*)&lds[e + 4] = v.q.z;
        *(unsigned*)&lds[e + 6] = v.q.w;
      }
    }
    __syncthreads();

    #pragma unroll 1
    for (int b = 0; b < 2; ++b) {
      const int hh = ng * 2 + b;
      const int h  = c * 4 + hh;

      bf16x8 qa = (arow < NTOK)
          ? *(const bf16x8*)&lds[AT_Q + arow * 384 + (((h * 4 + g) ^ (arow & 7)) << 3)]
          : zbf8();

      f32x4 sv[4];
      #pragma unroll
      for (int nt = 0; nt < 4; ++nt) {
        int tok = nt * 16 + li;
        bf16x8 kf = (tok < NTOK)
            ? *(const bf16x8*)&lds[AT_K + tok * 128 + (((hh * 4 + g) ^ (tok & 7)) << 3)]
            : zbf8();
        f32x4 z4 = (f32x4){0.f, 0.f, 0.f, 0.f};
        sv[nt] = __builtin_amdgcn_mfma_f32_16x16x32_bf16(kf, qa, z4, 0, 0, 0);
      }

      const float* cb = cmb + (size_t)(wi * HEADS + h) * (NTOK * NTOK);
      #pragma unroll
      for (int nt = 0; nt < 4; ++nt) {
        #pragma unroll
        for (int r4 = 0; r4 < 4; ++r4) {
          int tok = nt * 16 + g * 4 + r4;
          float v;
          if (tok < NTOK) {
            v = sv[nt][r4];
            if (arow < NTOK) v += cb[tok * NTOK + arow];
          } else {
            v = -1e30f;
          }
          sv[nt][r4] = v;
        }
      }

      float m = -1e30f;
      #pragma unroll
      for (int nt = 0; nt < 4; ++nt)
        #pragma unroll
        for (int r4 = 0; r4 < 4; ++r4) m = fmaxf(m, sv[nt][r4]);
      m = fmaxf(m, __shfl_xor(m, 16));
      m = fmaxf(m, __shfl_xor(m, 32));
      float s = 0.f;
      #pragma unroll
      for (int nt = 0; nt < 4; ++nt)
        #pragma unroll
        for (int r4 = 0; r4 < 4; ++r4) {
          float e = __expf(sv[nt][r4] - m);
          sv[nt][r4] = e;
          s += e;
        }
      s += __shfl_xor(s, 16);
      s += __shfl_xor(s, 32);
      float inv = 1.f / s;
      #pragma unroll
      for (int nt = 0; nt < 4; ++nt)
        #pragma unroll
        for (int r4 = 0; r4 < 4; ++r4) sv[nt][r4] *= inv;

      bf16x8 pa[2];
      #pragma unroll
      for (int k2 = 0; k2 < 2; ++k2) {
        BF8 pf;
        #pragma unroll
        for (int j = 0; j < 8; ++j) {
          int srcLane = (((g * 2 + (j >> 2)) & 3) << 4) | li;
          float v0 = __shfl(sv[k2 * 2][j & 3], srcLane);
          float v1 = __shfl(sv[k2 * 2 + 1][j & 3], srcLane);
          pf.u[j] = f2bf((g >= 2) ? v1 : v0);
        }
        pa[k2] = pf.v;
      }

      f32x4 oa[2];
      oa[0] = (f32x4){0.f, 0.f, 0.f, 0.f};
      oa[1] = (f32x4){0.f, 0.f, 0.f, 0.f};
      #pragma unroll
      for (int k2 = 0; k2 < 2; ++k2) {
        #pragma unroll
        for (int nt2 = 0; nt2 < 2; ++nt2) {
          BF8 vb;
          int ch = hh * 32 + nt2 * 16 + li;
          #pragma unroll
          for (int j = 0; j < 8; ++j) {
            int tok = k2 * 32 + g * 8 + j;
            vb.u[j] = (tok < NTOK) ? lds[AT_V + tok * 138 + ch] : (unsigned short)0;
          }
          oa[nt2] = __builtin_amdgcn_mfma_f32_16x16x32_bf16(pa[k2], vb.v, oa[nt2], 0, 0, 0);
        }
      }

      #pragma unroll
      for (int nt2 = 0; nt2 < 2; ++nt2) {
        int col = h * 32 + nt2 * 16 + li;
        #pragma unroll
        for (int r4 = 0; r4 < 4; ++r4) {
          int row = mgrp * 16 + g * 4 + r4;
          if (row < NTOK)
            Obuf[(rowbase + row) * 384 + col] = f2bf(oa[nt2][r4]);
        }
      }
    }
  }
}

extern "C" void kernel_launch(void* const* d_in, const int* in_sizes, int n_in,
                              void* d_out, int out_size, void* d_ws, size_t ws_size,
                              hipStream_t stream) {
  (void)in_sizes; (void)n_in; (void)out_size;
  const float* x          = (const float*)d_in[0];
  const float* mask       = (const float*)d_in[1];
  const float* qkv_w      = (const float*)d_in[2];
  const float* qkv_b      = (const float*)d_in[3];
  const float* proj_w     = (const float*)d_in[4];
  const float* proj_b     = (const float*)d_in[5];
  const float* bias_table = (const float*)d_in[6];
  const int*   rel_idx    = (const int*)d_in[7];
  float* out = (float*)d_out;

  char* ws = (char*)d_ws;
  size_t off = 0;
  unsigned short* wq  = (unsigned short*)(ws + off); off += (size_t)QKV_ELEMS * 2;
  unsigned short* wp  = (unsigned short*)(ws + off); off += (size_t)PROJ_ELEMS * 2;
  float*          qb2 = (float*)(ws + off);          off += (size_t)QKV_OC * 4;
  float*          cmb = (float*)(ws + off);          off += (size_t)CMB_ELEMS * 4;
  const size_t fixed = off;

  // batch size: prefer WB=1024 (qkv slice 116 MB -> L3-resident, full grid)
  const int cands[7] = {1024, 2048, 512, 4096, 256, 128, 64};
  int WB = 64;
  for (int ci = 0; ci < 7; ++ci) {
    size_t need = fixed + (size_t)cands[ci] * 49 * (1152 + 384) * 2;
    if (need <= ws_size) { WB = cands[ci]; break; }
  }
  unsigned short* qkv = (unsigned short*)(ws + fixed);
  unsigned short* xb  = qkv + (size_t)WB * 49 * 1152;   // O buffer (bf16)

  const int prep_total = QKV_ELEMS + PROJ_ELEMS + CMB_ELEMS + QKV_OC;
  prep_kernel<<<(prep_total + 255) / 256, 256, 0, stream>>>(
      qkv_w, proj_w, bias_table, rel_idx, mask, qkv_b, wq, wp, cmb, qb2);

  const int NB = 4096 / WB;
  const int Mrows = WB * 49;
  const int grid = (Mrows + 63) / 64;
  for (int b = 0; b < NB; ++b) {
    gemm_full<18, 1, 1><<<grid, 256, 0, stream>>>(
        (const void*)(x + (size_t)b * Mrows * 384), wq, qb2, (void*)qkv, Mrows);
    attn_kernel<<<WB, 512, 0, stream>>>(qkv, cmb, xb, b * WB);
    gemm_full<6, 0, 0><<<grid, 256, 0, stream>>>(
        (const void*)xb, wp, proj_b, (void*)(out + (size_t)b * Mrows * 384), Mrows);
  }
}